// Round 1
// baseline (491.275 us; speedup 1.0000x reference)
//
#include <hip/hip_runtime.h>
#include <cstdint>
#include <cstddef>

// R3 strategy:
//  1) absmax(x) & absmax(W) in ONE dispatch: grid-stride per-block partials
//     (no atomics), then a 2-block final-reduce -> sat[0]=sat_x, sat[1]=sat_w.
//  2) fused quantize: x -> int8 [M,K], W -> int8 [N,K] (exact reference ops:
//     scale = max(sat,1e-8)/127 ; rintf(v/scale) ; clip to [-128,127]).
//  3) int8 MFMA GEMM, m97 byte-geometry: 128x128 tile, BK=128 BYTES
//     (128 i8 elements -> 32 K-steps of 32 MFMA each, half the barrier-drain
//     events of the previous BK=64B version), global_load_lds width 16,
//     mfma_i32_16x16x64_i8.
//     LDS bank conflicts: global_load_lds forces LDS slot = base+lane*16, so
//     we swizzle WHICH global 16B chunk each lane fetches (pre-swizzled
//     source) and de-swizzle the ds_read address: slot = chunk ^ (row&7).
//     XCD-aware block swizzle (nwg=2048 % 8 == 0 -> simple chunked remap).

typedef int v4i __attribute__((ext_vector_type(4)));

__device__ __forceinline__ void async_copy16(const void* g, void* s) {
  __builtin_amdgcn_global_load_lds(
      (const __attribute__((address_space(1))) void*)g,
      (__attribute__((address_space(3))) void*)s, 16, 0, 0);
}

__device__ __forceinline__ float block_max(float m) {
  __shared__ float smax[4];
#pragma unroll
  for (int off = 32; off > 0; off >>= 1)
    m = fmaxf(m, __shfl_down(m, off, 64));
  if ((threadIdx.x & 63) == 0) smax[threadIdx.x >> 6] = m;
  __syncthreads();
  return fmaxf(fmaxf(smax[0], smax[1]), fmaxf(smax[2], smax[3]));
}

#define NBX 1024  // partial blocks for x
#define NBW 512   // partial blocks for W

__global__ __launch_bounds__(256) void absmax_partial_kernel(
    const float4* __restrict__ x, int xn4, const float4* __restrict__ w,
    int wn4, float* __restrict__ px, float* __restrict__ pw) {
  const float4* src;
  float* dst;
  int n4, bid, nb;
  if (blockIdx.x < NBX) {
    src = x; n4 = xn4; dst = px; bid = blockIdx.x; nb = NBX;
  } else {
    src = w; n4 = wn4; dst = pw; bid = blockIdx.x - NBX; nb = NBW;
  }
  float m = 0.0f;
  for (int i = bid * 256 + threadIdx.x; i < n4; i += nb * 256) {
    float4 v = src[i];
    m = fmaxf(m, fmaxf(fmaxf(fabsf(v.x), fabsf(v.y)),
                       fmaxf(fabsf(v.z), fabsf(v.w))));
  }
  m = block_max(m);
  if (threadIdx.x == 0) dst[bid] = m;
}

__global__ __launch_bounds__(256) void absmax_final_kernel(
    const float* __restrict__ px, const float* __restrict__ pw,
    float* __restrict__ sat) {
  const float* src = (blockIdx.x == 0) ? px : pw;
  const int n = (blockIdx.x == 0) ? NBX : NBW;
  float m = 0.0f;
  for (int i = threadIdx.x; i < n; i += 256) m = fmaxf(m, src[i]);
  m = block_max(m);
  if (threadIdx.x == 0) sat[blockIdx.x] = m;
}

__global__ __launch_bounds__(256) void quant_fused_kernel(
    const float4* __restrict__ x, int xn4, const float4* __restrict__ w,
    int wn4, const float* __restrict__ sat, int* __restrict__ xq,
    int* __restrict__ wq) {
  int i = blockIdx.x * 256 + threadIdx.x;
  float4 v;
  float scale;
  int* q;
  int qi;
  if (i < xn4) {
    v = x[i];
    scale = fmaxf(sat[0], 1e-8f) / 127.0f;
    q = xq; qi = i;
  } else {
    int j = i - xn4;
    if (j >= wn4) return;
    v = w[j];
    scale = fmaxf(sat[1], 1e-8f) / 127.0f;
    q = wq; qi = j;
  }
  int a = (int)fminf(fmaxf(rintf(v.x / scale), -128.0f), 127.0f);
  int b = (int)fminf(fmaxf(rintf(v.y / scale), -128.0f), 127.0f);
  int c = (int)fminf(fmaxf(rintf(v.z / scale), -128.0f), 127.0f);
  int d = (int)fminf(fmaxf(rintf(v.w / scale), -128.0f), 127.0f);
  q[qi] = (a & 255) | ((b & 255) << 8) | ((c & 255) << 16) | ((d & 255) << 24);
}

// C[m,n] = sum_k A[m,k]*B[n,k]  (A = x_int8 [M,K], B = w_int8 [N,K]).
// 128x128 tile, BK = 128 int8 elements (128 bytes per row).
__global__ __launch_bounds__(256) void i8_gemm_kernel(
    const signed char* __restrict__ Aq, const signed char* __restrict__ Bq,
    const float* __restrict__ bias, const float* __restrict__ sat,
    float* __restrict__ out, int M, int N, int K) {
  __shared__ signed char Als[128 * 128];
  __shared__ signed char Bls[128 * 128];

  const int tid = threadIdx.x;
  const int lane = tid & 63;
  const int wave = tid >> 6;
  const int wm = (wave & 1) * 64;
  const int wn = (wave >> 1) * 64;

  // XCD-aware block swizzle (bijective since nwg % 8 == 0 for this shape).
  const int nwg = gridDim.x * gridDim.y;
  int bid = blockIdx.y * gridDim.x + blockIdx.x;
  if ((nwg & 7) == 0) bid = (bid & 7) * (nwg >> 3) + (bid >> 3);
  const int N0 = (bid % gridDim.x) * 128;
  const int M0 = (bid / gridDim.x) * 128;

  // ---- staging (write side) ----
  // Thread t stages rows (srow + 32*r), r=0..3, chunk slot sb (8x16B chunks
  // per 128B row). LDS slot is FORCED to wave_base + lane*16 by
  // global_load_lds; slot (row, sb) holds global chunk cg = sb ^ (row&7).
  // row&7 == srow&7 (row-32r steps keep low 3 bits), so cg is loop-invariant.
  const int srow = tid >> 3;  // 0..31
  const int sb = tid & 7;     // LDS chunk slot 0..7
  const int cg = sb ^ (srow & 7);
  const signed char* Ag = Aq + (size_t)(M0 + srow) * K + cg * 16;
  const signed char* Bg = Bq + (size_t)(N0 + srow) * K + cg * 16;
  signed char* AlsP = &Als[srow * 128 + sb * 16];
  signed char* BlsP = &Bls[srow * 128 + sb * 16];

  // ---- read side ----
  // A-fragment for mfma_i32_16x16x64_i8: lane holds row (wm+t*16+r15),
  // k-bytes chunk c = ks*4 + (lane>>4) (ks = 64-elem K-slice 0/1).
  // That chunk sits at slot c ^ (row&7); row&7 == r15&7.
  const int r15 = lane & 15;
  const int rx = r15 & 7;
  const int q4 = lane >> 4;
  const int kb0 = ((q4) ^ rx) * 16;      // ks=0 de-swizzled byte offset
  const int kb1 = ((4 + q4) ^ rx) * 16;  // ks=1

  v4i acc[4][4] = {};

  for (int kt = 0; kt < K; kt += 128) {
    __syncthreads();
#pragma unroll
    for (int r = 0; r < 4; ++r) {
      async_copy16(Ag + kt + (size_t)(32 * r) * K, AlsP + 32 * r * 128);
      async_copy16(Bg + kt + (size_t)(32 * r) * K, BlsP + 32 * r * 128);
    }
    __syncthreads();

#pragma unroll
    for (int ks = 0; ks < 2; ++ks) {
      const int kb = ks ? kb1 : kb0;
      v4i af[4], bf[4];
#pragma unroll
      for (int t = 0; t < 4; ++t) {
        af[t] = *(const v4i*)&Als[(wm + t * 16 + r15) * 128 + kb];
        bf[t] = *(const v4i*)&Bls[(wn + t * 16 + r15) * 128 + kb];
      }
#pragma unroll
      for (int tm = 0; tm < 4; ++tm)
#pragma unroll
        for (int tn = 0; tn < 4; ++tn)
          acc[tm][tn] = __builtin_amdgcn_mfma_i32_16x16x64_i8(
              af[tm], bf[tn], acc[tm][tn], 0, 0, 0);
    }
  }

  const float act_s = fmaxf(sat[0], 1e-8f) / 127.0f;
  const float w_s = fmaxf(sat[1], 1e-8f) / 127.0f;
  const float bscale = act_s * w_s;

  // C/D layout (16x16 shapes): col = lane&15, row = (lane>>4)*4 + reg
#pragma unroll
  for (int tn = 0; tn < 4; ++tn) {
    const int col = N0 + wn + tn * 16 + r15;
    const float fb = rintf(bias[col] / bscale);
#pragma unroll
    for (int tm = 0; tm < 4; ++tm) {
      const int row0 = M0 + wm + tm * 16 + q4 * 4;
#pragma unroll
      for (int r = 0; r < 4; ++r) {
        out[(size_t)(row0 + r) * N + col] =
            ((float)acc[tm][tn][r] + fb) * bscale;
      }
    }
  }
}

extern "C" void kernel_launch(void* const* d_in, const int* in_sizes, int n_in,
                              void* d_out, int out_size, void* d_ws,
                              size_t ws_size, hipStream_t stream) {
  const float* x = (const float*)d_in[0];
  const float* W = (const float*)d_in[1];
  const float* b = (const float*)d_in[2];
  float* out = (float*)d_out;

  const int Dout = in_sizes[2];      // 4096
  const int K = in_sizes[1] / Dout;  // 4096
  const int M = in_sizes[0] / K;     // 8192
  const int N = Dout;

  // ws layout: sat[2] floats | px[NBX] | pw[NBW] | (8KB align) xq[M*K] | wq[N*K]
  float* sat = (float*)d_ws;
  float* px = sat + 16;
  float* pw = px + NBX;
  signed char* xq = (signed char*)d_ws + 8192;
  signed char* wq = xq + (size_t)M * K;

  const int xn4 = in_sizes[0] / 4;
  const int wn4 = in_sizes[1] / 4;

  absmax_partial_kernel<<<NBX + NBW, 256, 0, stream>>>(
      (const float4*)x, xn4, (const float4*)W, wn4, px, pw);
  absmax_final_kernel<<<2, 256, 0, stream>>>(px, pw, sat);
  quant_fused_kernel<<<(xn4 + wn4 + 255) / 256, 256, 0, stream>>>(
      (const float4*)x, xn4, (const float4*)W, wn4, sat, (int*)xq, (int*)wq);

  dim3 grid(N / 128, M / 128);
  i8_gemm_kernel<<<grid, 256, 0, stream>>>(xq, wq, b, sat, out, M, N, K);
}